// Round 8
// baseline (202.126 us; speedup 1.0000x reference)
//
#include <hip/hip_runtime.h>
#include <cstddef>
#include <cstdint>

// B=256, N=32, F=40, H=M=100, EF=4, OUT=128, 3 passes.
// SINGLE fused kernel: no prep pass, no workspace. Weight fragments gathered
// in-kernel (r5's code, values identical to prep_frags4) into registers,
// pinned at 2 waves/EU (r5's spill was the unpinned 128-VGPR cap; r7 proved
// the pin holds the same resident set without spill):
//   Am[4][4] W_msg (64 VGPR)  Ai[3][4] W_ih (48)  Ah[3][4] W_hh (48)
// Pass loop touches ZERO global memory; barriers wait only on LDS.
#define B_   256
#define N_   32
#define F_   40
#define H_   100
#define OUT_ 128
#define TB   512          // 8 waves/block, 1 block/CU, 2 waves/SIMD (pinned)
#define XCS  168          // XcH row stride (shorts), 16B-multiple
#define XMS  136          // XmH row stride (shorts), 16B-multiple
#define AWS  40           // Aw row stride (shorts): padded (no 8-way conflict)
#define ZSP  40           // Zs row stride (shorts)

using bf16x8 = __attribute__((ext_vector_type(8))) short;   // 8 bf16 (4 VGPRs)
using f32x4  = __attribute__((ext_vector_type(4))) float;   // MFMA C/D

#define MFMA(a,b,c) __builtin_amdgcn_mfma_f32_16x16x32_bf16((a),(b),(c),0,0,0)

__device__ __forceinline__ float sigmoidf_(float x){ return 1.0f/(1.0f+__expf(-x)); }
__device__ __forceinline__ float tanhf_(float x){           // fast tanh via __expf
  float e = __expf(2.0f*x);
  return 1.0f - 2.0f/(e+1.0f);
}
__device__ __forceinline__ float bf2f(short s){ return __uint_as_float(((uint32_t)(uint16_t)s)<<16); }
__device__ __forceinline__ short f2bf(float x){             // round-to-nearest-even
  uint32_t u = __float_as_uint(x);
  return (short)((u + 0x7FFFu + ((u>>16)&1u))>>16);
}

// ---------------------------------------------------------------------------
// Fused MPNN, fully weight-stationary, single kernel.
// 8 waves; wave w = jmt tile (w<7 active), BOTH node halves per wave.
// Pass structure (r6's best-measured variant), 2 barriers/pass:
//  R0: cache 8 XcH frags once (serve Z's H^T AND hh's B) -> per-t 8 Za MFMA
//      (resident Am) + 8 Zs stores -> 24 hh MFMA (hide store->read) ->
//      4 az reads + 8 agg MFMA -> XmH write                            bar
//  R1: ih gates (r/z accumulate INTO Chh, pre-summed biases) + GRU     bar
// Readout: Wg/We gathered inline (hi+lo bf16 split), Wo tail unchanged.
// ---------------------------------------------------------------------------
__global__ __launch_bounds__(TB)
__attribute__((amdgpu_waves_per_eu(2, 2)))
void mpnn_fused(
    const float* __restrict__ nodes, const float* __restrict__ edges,
    const float* __restrict__ Wmsg, const float* __restrict__ Wih,
    const float* __restrict__ Whh,
    const float* __restrict__ b_ih, const float* __restrict__ b_hh,
    const float* __restrict__ Wg, const float* __restrict__ bg,
    const float* __restrict__ We, const float* __restrict__ be,
    const float* __restrict__ Wo, const float* __restrict__ bo,
    float* __restrict__ out){
  const int b = blockIdx.x;
  const int tid = threadIdx.x;
  const int lane = tid & 63;
  const int w = tid >> 6;                         // 0..7

  __shared__ short XcH[32*XCS];                   // cat: h | nodes(100..139) | 0
  __shared__ short XmH[32*XMS];                   // messages (bf16) [n][m]
  __shared__ short Aw[4][32*AWS];                 // adjacency [t][n][g] (bf16)
  __shared__ short Zs[7*4*16*ZSP];                // [wave][t][16][ZSP] Z scratch
  __shared__ float sh_ge[H_];
  __shared__ float sh_part[4][OUT_];              // Wo-tail partials
  __shared__ int   sh_msk[N_];                    // node-has-edges mask

  // ---- zero LDS (rows never written later must be 0) -----------------------
  for (int i=tid;i<(32*XCS)/2;i+=TB){ ((int*)XcH)[i]=0; }
  for (int i=tid;i<(32*XMS)/2;i+=TB){ ((int*)XmH)[i]=0; }
  if (tid < H_) sh_ge[tid]=0.0f;
  __syncthreads();

  // ---- edge staging: adjacency planes + ballot mask ------------------------
  for (int e=tid; e<N_*N_; e+=TB){
    int n = e>>5, g = e&31;
    const float4 ev = *(const float4*)(edges + (((size_t)b*N_+n)*N_+g)*4);
    float adj = ev.x+ev.y+ev.z+ev.w;                 // one-hot sums, >=0
    unsigned long long bal = __ballot(adj != 0.0f);  // wave covers 2 n-rows
    if (lane == 0)  sh_msk[n] = ((int)(bal & 0xFFFFFFFFull)) != 0;
    if (lane == 32) sh_msk[n] = ((int)(bal >> 32)) != 0;
    Aw[0][n*AWS+g] = f2bf(ev.x);
    Aw[1][n*AWS+g] = f2bf(ev.y);
    Aw[2][n*AWS+g] = f2bf(ev.z);
    Aw[3][n*AWS+g] = f2bf(ev.w);
  }
  for (int p=tid; p<N_*F_; p+=TB){
    int n = p/F_, f = p%F_;
    float x = nodes[((size_t)b*N_+n)*F_ + f];
    short hi = f2bf(x);
    XcH[n*XCS+f]=hi;                            // h init rows 0..39
    XcH[n*XCS+100+f]=hi;                        // cat-tail rows 100..139
  }

  const int jmt = w;                            // one jmt per wave (w<7)
  const bool task = (w < 7);
  const int c16 = lane & 15;
  const int q   = lane >> 4;                    // 0..3
  const int boff = q*8;                         // k-offset in B/A frags
  const int rowbase = jmt*16 + q*4;             // this lane's 4 output rows
  const int n0 = c16, n1 = 16 + c16;            // both node halves

  // ---- in-kernel weight gather (per wave, once; == prep_frags4 values) -----
  bf16x8 Am[4][4], Ai[3][4], Ah[3][4];
  float bs0[4],bs1[4],bi2[4],bh2[4];
  float hst0[4]={0.f,0.f,0.f,0.f}, hst1[4]={0.f,0.f,0.f,0.f};
  if (task){
    const int mg = jmt*16 + c16;                // this lane's A-row
    const bool mok = (mg < 100);
#pragma unroll
    for (int t=0;t<4;++t){
#pragma unroll
      for (int ks=0;ks<4;++ks){
        bf16x8 f;
#pragma unroll
        for (int jj=0;jj<8;++jj){
          int h = ks*32 + q*8 + jj;
          float v = (mok && h<100) ? Wmsg[((size_t)(mg*100+h))*4 + t] : 0.0f;
          f[jj] = f2bf(v);
        }
        Am[t][ks] = f;
      }
    }
#pragma unroll
    for (int mat=0;mat<3;++mat){
      const size_t roff = (size_t)(mat*100 + (mok ? mg : 0))*100;
#pragma unroll
      for (int ks=0;ks<4;++ks){
        bf16x8 fi, fh;
#pragma unroll
        for (int jj=0;jj<8;++jj){
          int k = ks*32 + q*8 + jj;
          bool ok = mok && (k < 100);
          float vi = ok ? Wih[roff + k] : 0.0f;
          float vh = ok ? Whh[roff + k] : 0.0f;
          fi[jj] = f2bf(vi);
          fh[jj] = f2bf(vh);
        }
        Ai[mat][ks] = fi;
        Ah[mat][ks] = fh;
      }
    }
#pragma unroll
    for (int r=0;r<4;++r){
      int row = rowbase + r;
      bool ok = row < 100;
      bs0[r] = ok ? (b_ih[row]     + b_hh[row])     : 0.0f;  // r-gate bias
      bs1[r] = ok ? (b_ih[100+row] + b_hh[100+row]) : 0.0f;  // z-gate bias
      bi2[r] = ok ? b_ih[200+row] : 0.0f;
      bh2[r] = ok ? b_hh[200+row] : 0.0f;
      if (row < F_){
        hst0[r] = nodes[((size_t)b*N_+n0)*F_ + row];
        hst1[r] = nodes[((size_t)b*N_+n1)*F_ + row];
      }
    }
  }
  __syncthreads();

  for (int pass=0; pass<3; ++pass){
    f32x4 Chh[3][2];
#pragma unroll
    for (int m3=0;m3<3;++m3){ Chh[m3][0]=(f32x4)0.0f; Chh[m3][1]=(f32x4)0.0f; }
    // ---- region 0: Z (t-outer, resident Am, cached x) -> hh -> agg ---------
    if (task){
      // XcH fragments, read ONCE: rows n0/n1 serve BOTH Z's H^T and hh's B.
      bf16x8 x0[4], x1[4];
#pragma unroll
      for (int ks=0;ks<4;++ks){
        x0[ks] = *(const bf16x8*)&XcH[n0*XCS + ks*32 + boff];
        x1[ks] = *(const bf16x8*)&XcH[n1*XCS + ks*32 + boff];
      }
      // Z_t = Wmsg_t @ H^T per t; stores issued immediately, reads deferred
      // until after the hh block (latency hidden under 24 MFMAs).
#pragma unroll
      for (int t=0;t<4;++t){
        f32x4 Za0=(f32x4)0.0f, Za1=(f32x4)0.0f;
        Za0 = MFMA(Am[t][0],x0[0],Za0); Za0 = MFMA(Am[t][1],x0[1],Za0);
        Za0 = MFMA(Am[t][2],x0[2],Za0); Za0 = MFMA(Am[t][3],x0[3],Za0);
        Za1 = MFMA(Am[t][0],x1[0],Za1); Za1 = MFMA(Am[t][1],x1[1],Za1);
        Za1 = MFMA(Am[t][2],x1[2],Za1); Za1 = MFMA(Am[t][3],x1[3],Za1);
        int zb = (w*4+t)*16*ZSP;
#pragma unroll
        for (int r=0;r<4;++r){                   // D: row=j-local, col=g
          Zs[zb + (q*4+r)*ZSP + c16]      = f2bf(Za0[r]);
          Zs[zb + (q*4+r)*ZSP + c16 + 16] = f2bf(Za1[r]);
        }
      }
      // hh gates, both halves, resident Ah (independent of Zs -> hides stores)
#pragma unroll
      for (int m3=0;m3<3;++m3){
#pragma unroll
        for (int ks=0;ks<4;++ks){
          Chh[m3][0] = MFMA(Ah[m3][ks], x0[ks], Chh[m3][0]);
          Chh[m3][1] = MFMA(Ah[m3][ks], x1[ks], Chh[m3][1]);
        }
      }
      // aggregation: Xm += Z_t @ A_t^T (single LDS round-trip per pass)
      f32x4 Cm0=(f32x4)0.0f, Cm1=(f32x4)0.0f;
#pragma unroll
      for (int t=0;t<4;++t){
        int zb = (w*4+t)*16*ZSP;
        bf16x8 az  = *(const bf16x8*)&Zs[zb + c16*ZSP + boff];  // same-wave
        bf16x8 bt0 = *(const bf16x8*)&Aw[t][n0*AWS + boff];
        bf16x8 bt1 = *(const bf16x8*)&Aw[t][n1*AWS + boff];
        Cm0 = MFMA(az, bt0, Cm0);
        Cm1 = MFMA(az, bt1, Cm1);
      }
      if (rowbase < 100){                        // quads never straddle 100
        short4 pk0, pk1;
        pk0.x=f2bf(Cm0[0]); pk0.y=f2bf(Cm0[1]); pk0.z=f2bf(Cm0[2]); pk0.w=f2bf(Cm0[3]);
        pk1.x=f2bf(Cm1[0]); pk1.y=f2bf(Cm1[1]); pk1.z=f2bf(Cm1[2]); pk1.w=f2bf(Cm1[3]);
        *(short4*)&XmH[n0*XMS + rowbase] = pk0;
        *(short4*)&XmH[n1*XMS + rowbase] = pk1;
      }
    }
    __syncthreads();
    // ---- region 1: ih gates (r/z accumulate into Chh) + GRU (reg state) ----
    if (task){
      f32x4 Ci2a=(f32x4)0.0f, Ci2b=(f32x4)0.0f;
#pragma unroll
      for (int ks=0;ks<4;++ks){
        bf16x8 m0 = *(const bf16x8*)&XmH[n0*XMS + ks*32 + boff];
        bf16x8 m1 = *(const bf16x8*)&XmH[n1*XMS + ks*32 + boff];
        Chh[0][0] = MFMA(Ai[0][ks], m0, Chh[0][0]);   // gi_r + gh_r fused
        Chh[0][1] = MFMA(Ai[0][ks], m1, Chh[0][1]);
        Chh[1][0] = MFMA(Ai[1][ks], m0, Chh[1][0]);   // gi_z + gh_z fused
        Chh[1][1] = MFMA(Ai[1][ks], m1, Chh[1][1]);
        Ci2a      = MFMA(Ai[2][ks], m0, Ci2a);        // gi_n separate
        Ci2b      = MFMA(Ai[2][ks], m1, Ci2b);
      }
      if (rowbase < 100){
        bool k0 = sh_msk[n0] != 0, k1 = sh_msk[n1] != 0;
        short4 pk0, pk1;
#pragma unroll
        for (int r=0;r<4;++r){
          {
            float ho = hst0[r];
            float rr = sigmoidf_(Chh[0][0][r] + bs0[r]);
            float zz = sigmoidf_(Chh[1][0][r] + bs1[r]);
            float nn = tanhf_(Ci2a[r] + bi2[r] + rr*(Chh[2][0][r] + bh2[r]));
            float hnew = (1.0f-zz)*nn + zz*ho;
            if (!k0) hnew = ho;
            hst0[r] = hnew;
            ((short*)&pk0)[r] = f2bf(hnew);
          }
          {
            float ho = hst1[r];
            float rr = sigmoidf_(Chh[0][1][r] + bs0[r]);
            float zz = sigmoidf_(Chh[1][1][r] + bs1[r]);
            float nn = tanhf_(Ci2b[r] + bi2[r] + rr*(Chh[2][1][r] + bh2[r]));
            float hnew = (1.0f-zz)*nn + zz*ho;
            if (!k1) hnew = ho;
            hst1[r] = hnew;
            ((short*)&pk1)[r] = f2bf(hnew);
          }
        }
        *(short4*)&XcH[n0*XCS + rowbase] = pk0;
        *(short4*)&XcH[n1*XCS + rowbase] = pk1;
      }
    }
    __syncthreads();
  }

  // ---- readout: gate/emb GEMMs (A hi+lo gathered inline), masked sum -------
  if (task){
    const int jg = jmt*16 + c16;
    const bool jok = jg < 100;
    bf16x8 rb0[5], rb1[5];
#pragma unroll
    for (int ks=0;ks<5;++ks){
      rb0[ks] = *(const bf16x8*)&XcH[n0*XCS + ks*32 + boff];
      rb1[ks] = *(const bf16x8*)&XcH[n1*XCS + ks*32 + boff];
    }
    f32x4 Cg0=(f32x4)0.0f, Cg1=(f32x4)0.0f, Ce0=(f32x4)0.0f, Ce1=(f32x4)0.0f;
#pragma unroll
    for (int ks=0;ks<5;++ks){                    // Wg^T, K=140 (hi+lo split)
      bf16x8 gh, gl;
#pragma unroll
      for (int jj=0;jj<8;++jj){
        int k = ks*32 + q*8 + jj;
        float v = (jok && k<140) ? Wg[(size_t)k*100 + jg] : 0.0f;
        short hi = f2bf(v);
        short lo = f2bf(v - bf2f(hi));
        gh[jj]=hi; gl[jj]=lo;
      }
      Cg0 = MFMA(gh, rb0[ks], Cg0); Cg0 = MFMA(gl, rb0[ks], Cg0);
      Cg1 = MFMA(gh, rb1[ks], Cg1); Cg1 = MFMA(gl, rb1[ks], Cg1);
    }
#pragma unroll
    for (int ks=0;ks<4;++ks){                    // We^T, K=100 (hi+lo split)
      bf16x8 eh, el;
#pragma unroll
      for (int jj=0;jj<8;++jj){
        int k = ks*32 + q*8 + jj;
        float v = (jok && k<100) ? We[(size_t)k*100 + jg] : 0.0f;
        short hi = f2bf(v);
        short lo = f2bf(v - bf2f(hi));
        eh[jj]=hi; el[jj]=lo;
      }
      Ce0 = MFMA(eh, rb0[ks], Ce0); Ce0 = MFMA(el, rb0[ks], Ce0);
      Ce1 = MFMA(eh, rb1[ks], Ce1); Ce1 = MFMA(el, rb1[ks], Ce1);
    }
    bool k0 = sh_msk[n0] != 0, k1 = sh_msk[n1] != 0;
#pragma unroll
    for (int r=0;r<4;++r){
      int row = rowbase + r;
      float v0 = 0.0f, v1 = 0.0f;
      if (row<100){
        float g0 = sigmoidf_(Cg0[r] + bg[row]);
        float g1 = sigmoidf_(Cg1[r] + bg[row]);
        float e0 = g0*(Ce0[r] + be[row]);
        float e1 = g1*(Ce1[r] + be[row]);
        v0 = k0 ? e0 : 0.0f;
        v1 = k1 ? e1 : 0.0f;
      }
      float v = v0 + v1;                       // halves sum into same graph-emb
      v += __shfl_xor(v, 1);                   // reduce across 16 cols
      v += __shfl_xor(v, 2);
      v += __shfl_xor(v, 4);
      v += __shfl_xor(v, 8);
      if (row<100 && (lane&15)==0) atomicAdd(&sh_ge[row], v);
    }
  }
  __syncthreads();
  // ---- out = graph_emb @ Wo + bo : 512 threads, 4 k-chunks of 25 -----------
  {
    int o = tid & 127, qq = tid >> 7;          // lanes consecutive in o -> coalesced
    float s = 0.0f;
    int k0 = 25*qq;
#pragma unroll 5
    for (int k=k0; k<k0+25; ++k) s += sh_ge[k]*Wo[k*OUT_+o];
    sh_part[qq][o] = s;
  }
  __syncthreads();
  if (tid < OUT_){
    out[(size_t)b*OUT_ + tid] = bo[tid] + sh_part[0][tid] + sh_part[1][tid]
                              + sh_part[2][tid] + sh_part[3][tid];
  }
}

extern "C" void kernel_launch(void* const* d_in, const int* in_sizes, int n_in,
                              void* d_out, int out_size, void* d_ws, size_t ws_size,
                              hipStream_t stream){
  const float* nodes = (const float*)d_in[0];
  const float* edges = (const float*)d_in[1];
  const float* W_msg = (const float*)d_in[2];
  const float* W_ih  = (const float*)d_in[3];
  const float* W_hh  = (const float*)d_in[4];
  const float* b_ih  = (const float*)d_in[5];
  const float* b_hh  = (const float*)d_in[6];
  const float* Wg    = (const float*)d_in[7];
  const float* bg    = (const float*)d_in[8];
  const float* We    = (const float*)d_in[9];
  const float* be    = (const float*)d_in[10];
  const float* Wo    = (const float*)d_in[11];
  const float* bo    = (const float*)d_in[12];
  (void)d_ws; (void)ws_size;                   // single kernel, no workspace

  mpnn_fused<<<B_, TB, 0, stream>>>(nodes, edges, W_msg, W_ih, W_hh,
                                    b_ih, b_hh, Wg, bg, We, be, Wo, bo,
                                    (float*)d_out);
}

// Round 9
// 109.161 us; speedup vs baseline: 1.8516x; 1.8516x over previous
//
#include <hip/hip_runtime.h>
#include <cstddef>
#include <cstdint>

// B=256, N=32, F=40, H=M=100, EF=4, OUT=128, 3 passes.
#define B_   256
#define N_   32
#define F_   40
#define H_   100
#define OUT_ 128
#define TB   512          // 8 waves/block, 1 block/CU
#define XCS  168          // XcH row stride (shorts), 16B-multiple, 2-way banks
#define XMS  136          // XmH row stride (shorts), 16B-multiple
#define AWS  40           // Aw row stride (shorts): padded (no 8-way conflict)
#define ZSP  40           // Zs row stride (shorts)
#define NBLK 343          // AFhi blocks: 112 msg + 168 GRU + 35 Wg + 28 We
#define NLO  63           // AFlo blocks (readout lo)

using bf16x8 = __attribute__((ext_vector_type(8))) short;   // 8 bf16 (4 VGPRs)
using f32x4  = __attribute__((ext_vector_type(4))) float;   // MFMA C/D

#define MFMA(a,b,c) __builtin_amdgcn_mfma_f32_16x16x32_bf16((a),(b),(c),0,0,0)

__device__ __forceinline__ float sigmoidf_(float x){ return 1.0f/(1.0f+__expf(-x)); }
__device__ __forceinline__ float tanhf_(float x){           // fast tanh via __expf
  float e = __expf(2.0f*x);
  return 1.0f - 2.0f/(e+1.0f);
}
__device__ __forceinline__ float bf2f(short s){ return __uint_as_float(((uint32_t)(uint16_t)s)<<16); }
__device__ __forceinline__ short f2bf(float x){             // round-to-nearest-even
  uint32_t u = __float_as_uint(x);
  return (short)((u + 0x7FFFu + ((u>>16)&1u))>>16);
}
__device__ __forceinline__ void bsplit(float x, short& hi, short& lo){
  hi = f2bf(x);
  lo = f2bf(x - bf2f(hi));
}

// ---------------------------------------------------------------------------
// Weight pre-pack v4 (proven trivial-copy layout): SLOT-indexed, OOR slots 0.
// The packed form is what makes mpnn's weight reads REMATERIALIZABLE under
// the 128-VGPR cap (r5/r8 lesson: in-kernel gathered weights spill instead).
//   [0,112)   W_msg : t*28 + jmt*4 + ks        A[m][h]=W_msg[m, h, t]
//   [112,280) GRU   : 112+mat*28+jmt*4+ks      mat: ihr,ihz,ihn,hhr,hhz,hhn
//   [280,315) Wg^T  : 280+jmt*5+ks (K=140)     A[j][k]=Wg[k, j]  (hi+lo)
//   [315,343) We^T  : 315+jmt*4+ks             A[j][k]=We[k, j]  (hi+lo)
// ---------------------------------------------------------------------------
__global__ void prep_frags4(const float* __restrict__ Wmsg,
                            const float* __restrict__ Wih,
                            const float* __restrict__ Whh,
                            const float* __restrict__ Wg,
                            const float* __restrict__ We,
                            short* __restrict__ AFhi,
                            short* __restrict__ AFlo){
  int slot = blockIdx.x*blockDim.x + threadIdx.x;
  if (slot >= NBLK*512) return;
  int blk = slot>>9, r = slot&511, lane = r>>3, jj = r&7;
  int m = lane&15, q = lane>>4, kl = q*8+jj;
  float v = 0.0f;
  if (blk < 112){
    int t = blk/28, rem = blk%28, jmt = rem>>2, ks = rem&3;
    int mg = jmt*16+m, h = ks*32+kl;
    if (mg<100 && h<100) v = Wmsg[(mg*100+h)*4 + t];
    AFhi[slot] = f2bf(v);
  } else if (blk < 280){
    int bb = blk-112, mat = bb/28, rem = bb%28, jmt = rem>>2, ks = rem&3;
    int mg = jmt*16+m, k = ks*32+kl;
    if (mg<100 && k<100)
      v = (mat<3) ? Wih[(mat*100+mg)*100+k] : Whh[((mat-3)*100+mg)*100+k];
    AFhi[slot] = f2bf(v);
  } else if (blk < 315){
    int bb = blk-280, jmt = bb/5, ks = bb%5;
    int mg = jmt*16+m, k = ks*32+kl;
    if (mg<100 && k<140) v = Wg[k*100+mg];
    short hi,lo; bsplit(v,hi,lo);
    AFhi[slot] = hi;
    AFlo[(size_t)(blk-280)*512 + r] = lo;
  } else {
    int bb = blk-315, jmt = bb>>2, ks = bb&3;
    int mg = jmt*16+m, k = ks*32+kl;
    if (mg<100 && k<100) v = We[k*100+mg];
    short hi,lo; bsplit(v,hi,lo);
    AFhi[slot] = hi;
    AFlo[(size_t)(blk-280)*512 + r] = lo;
  }
}

// ---------------------------------------------------------------------------
// Fused MPNN (r4 structure, measured best). 8 waves; wave w = jmt tile (w<7
// active), BOTH node halves per wave. GRU A-frags loaded from packed AFhi
// (rematerializable under the 128-VGPR cap); msg A-frags streamed per pass.
// NEW: wave 7 (idle in r4) stages Wo (51.2 KB) into LDS across the 6 pass-
// loop barrier intervals -> readout tail reads LDS instead of cold L2/HBM.
// Pass structure, 2 barriers/pass:
//  R0: read 8 XcH frags once -> 4x(Z MFMAs + Zs stores) -> 24 hh MFMA
//      (hide store->read) -> 4 az reads + 8 agg MFMA -> XmH write      bar
//  R1: ih gates (r/z accumulate INTO Chh, pre-summed biases) + GRU     bar
// ---------------------------------------------------------------------------
__global__ __launch_bounds__(TB, 2) void mpnn_mfma(
    const float* __restrict__ nodes, const float* __restrict__ edges,
    const short* __restrict__ AFhi, const short* __restrict__ AFlo,
    const float* __restrict__ b_ih, const float* __restrict__ b_hh,
    const float* __restrict__ bg, const float* __restrict__ be,
    const float* __restrict__ Wo, const float* __restrict__ bo,
    float* __restrict__ out){
  const int b = blockIdx.x;
  const int tid = threadIdx.x;
  const int lane = tid & 63;
  const int w = tid >> 6;                         // 0..7

  __shared__ short XcH[32*XCS];                   // cat: h | nodes(100..139) | 0
  __shared__ short XmH[32*XMS];                   // messages (bf16) [n][m]
  __shared__ short Aw[4][32*AWS];                 // adjacency [t][n][g] (bf16)
  __shared__ short Zs[7*4*16*ZSP];                // [wave][t][16][ZSP] Z scratch
  __shared__ float WoL[H_*OUT_];                  // Wo staged by wave 7 (51.2KB)
  __shared__ float sh_ge[H_];
  __shared__ float sh_part[4][OUT_];              // Wo-tail partials
  __shared__ int   sh_msk[N_];                    // node-has-edges mask

  // ---- zero LDS (rows never written later must be 0) -----------------------
  for (int i=tid;i<(32*XCS)/2;i+=TB){ ((int*)XcH)[i]=0; }
  for (int i=tid;i<(32*XMS)/2;i+=TB){ ((int*)XmH)[i]=0; }
  if (tid < H_) sh_ge[tid]=0.0f;
  __syncthreads();

  // ---- edge staging: adjacency planes + ballot mask ------------------------
  for (int e=tid; e<N_*N_; e+=TB){
    int n = e>>5, g = e&31;
    const float4 ev = *(const float4*)(edges + (((size_t)b*N_+n)*N_+g)*4);
    float adj = ev.x+ev.y+ev.z+ev.w;                 // one-hot sums, >=0
    unsigned long long bal = __ballot(adj != 0.0f);  // wave covers 2 n-rows
    if (lane == 0)  sh_msk[n] = ((int)(bal & 0xFFFFFFFFull)) != 0;
    if (lane == 32) sh_msk[n] = ((int)(bal >> 32)) != 0;
    Aw[0][n*AWS+g] = f2bf(ev.x);
    Aw[1][n*AWS+g] = f2bf(ev.y);
    Aw[2][n*AWS+g] = f2bf(ev.z);
    Aw[3][n*AWS+g] = f2bf(ev.w);
  }
  for (int p=tid; p<N_*F_; p+=TB){
    int n = p/F_, f = p%F_;
    float x = nodes[((size_t)b*N_+n)*F_ + f];
    short hi = f2bf(x);
    XcH[n*XCS+f]=hi;                            // h init rows 0..39
    XcH[n*XCS+100+f]=hi;                        // cat-tail rows 100..139
  }

  const int jmt = w;                            // one jmt per wave (w<7)
  const bool task = (w < 7);
  const int c16 = lane & 15;
  const int q   = lane >> 4;                    // 0..3
  const int boff = q*8;                         // k-offset in B/A frags
  const int rowbase = jmt*16 + q*4;             // this lane's 4 output rows
  const int n0 = c16, n1 = 16 + c16;            // both node halves

  // ---- register-resident GRU A-frags (rematerializable from AFhi) ----------
  bf16x8 Ai[3][4], Ah[3][4];
  if (task){
#pragma unroll
    for (int mat=0; mat<3; ++mat){
#pragma unroll
      for (int ks=0; ks<4; ++ks){
        Ai[mat][ks] = *(const bf16x8*)(AFhi + ((size_t)(112 + mat*28 + jmt*4 + ks))*512 + lane*8);
        Ah[mat][ks] = *(const bf16x8*)(AFhi + ((size_t)(112 + (3+mat)*28 + jmt*4 + ks))*512 + lane*8);
      }
    }
  }
  // ---- register-resident GRU biases (pre-summed r/z; rows >=100 dead) ------
  float bs0[4],bs1[4],bi2[4],bh2[4];
  float hst0[4]={0.f,0.f,0.f,0.f}, hst1[4]={0.f,0.f,0.f,0.f};
  if (task){
#pragma unroll
    for (int r=0;r<4;++r){
      int row = rowbase + r;
      bool ok = row < 100;
      bs0[r] = ok ? (b_ih[row]     + b_hh[row])     : 0.0f;
      bs1[r] = ok ? (b_ih[100+row] + b_hh[100+row]) : 0.0f;
      bi2[r] = ok ? b_ih[200+row] : 0.0f;
      bh2[r] = ok ? b_hh[200+row] : 0.0f;
      if (row < F_){
        hst0[r] = nodes[((size_t)b*N_+n0)*F_ + row];
        hst1[r] = nodes[((size_t)b*N_+n1)*F_ + row];
      }
    }
  }
  __syncthreads();

  for (int pass=0; pass<3; ++pass){
    f32x4 Chh[3][2];
#pragma unroll
    for (int m3=0;m3<3;++m3){ Chh[m3][0]=(f32x4)0.0f; Chh[m3][1]=(f32x4)0.0f; }
    // ---- region 0: Z (streamed Am) -> Zs -> hh -> agg ----------------------
    if (task){
      // XcH fragments, read ONCE: rows n0/n1 serve BOTH Z's H^T and hh's B.
      bf16x8 x0[4], x1[4];
#pragma unroll
      for (int ks=0;ks<4;++ks){
        x0[ks] = *(const bf16x8*)&XcH[n0*XCS + ks*32 + boff];
        x1[ks] = *(const bf16x8*)&XcH[n1*XCS + ks*32 + boff];
      }
      // Z_t = Wmsg_t @ H^T per t; stores issued immediately, reads deferred
      // until after the hh block (latency hidden under 24 MFMAs).
#pragma unroll
      for (int t=0;t<4;++t){
        const short* pa = AFhi + ((size_t)(t*28 + jmt*4))*512 + lane*8;
        bf16x8 a0 = *(const bf16x8*)(pa);
        bf16x8 a1 = *(const bf16x8*)(pa+512);
        bf16x8 a2 = *(const bf16x8*)(pa+1024);
        bf16x8 a3 = *(const bf16x8*)(pa+1536);
        f32x4 Za0=(f32x4)0.0f, Za1=(f32x4)0.0f;
        Za0 = MFMA(a0,x0[0],Za0); Za0 = MFMA(a1,x0[1],Za0);
        Za0 = MFMA(a2,x0[2],Za0); Za0 = MFMA(a3,x0[3],Za0);
        Za1 = MFMA(a0,x1[0],Za1); Za1 = MFMA(a1,x1[1],Za1);
        Za1 = MFMA(a2,x1[2],Za1); Za1 = MFMA(a3,x1[3],Za1);
        int zb = (w*4+t)*16*ZSP;
#pragma unroll
        for (int r=0;r<4;++r){                   // D: row=j-local, col=g
          Zs[zb + (q*4+r)*ZSP + c16]      = f2bf(Za0[r]);
          Zs[zb + (q*4+r)*ZSP + c16 + 16] = f2bf(Za1[r]);
        }
      }
      // hh gates, both halves (independent of Zs -> hides stores)
#pragma unroll
      for (int m3=0;m3<3;++m3){
#pragma unroll
        for (int ks=0;ks<4;++ks){
          Chh[m3][0] = MFMA(Ah[m3][ks], x0[ks], Chh[m3][0]);
          Chh[m3][1] = MFMA(Ah[m3][ks], x1[ks], Chh[m3][1]);
        }
      }
      // aggregation: Xm += Z_t @ A_t^T (single LDS round-trip per pass)
      f32x4 Cm0=(f32x4)0.0f, Cm1=(f32x4)0.0f;
#pragma unroll
      for (int t=0;t<4;++t){
        int zb = (w*4+t)*16*ZSP;
        bf16x8 az  = *(const bf16x8*)&Zs[zb + c16*ZSP + boff];  // same-wave
        bf16x8 bt0 = *(const bf16x8*)&Aw[t][n0*AWS + boff];
        bf16x8 bt1 = *(const bf16x8*)&Aw[t][n1*AWS + boff];
        Cm0 = MFMA(az, bt0, Cm0);
        Cm1 = MFMA(az, bt1, Cm1);
      }
      if (rowbase < 100){                        // quads never straddle 100
        short4 pk0, pk1;
        pk0.x=f2bf(Cm0[0]); pk0.y=f2bf(Cm0[1]); pk0.z=f2bf(Cm0[2]); pk0.w=f2bf(Cm0[3]);
        pk1.x=f2bf(Cm1[0]); pk1.y=f2bf(Cm1[1]); pk1.z=f2bf(Cm1[2]); pk1.w=f2bf(Cm1[3]);
        *(short4*)&XmH[n0*XMS + rowbase] = pk0;
        *(short4*)&XmH[n1*XMS + rowbase] = pk1;
      }
    } else if (w == 7){
      // wave 7: stage Wo chunk (interval 2*pass) into LDS (3200 float4 total)
      int iv = pass*2;
      for (int i4 = iv*544 + lane; i4 < 3200 && i4 < (iv+1)*544; i4 += 64)
        ((float4*)WoL)[i4] = ((const float4*)Wo)[i4];
    }
    __syncthreads();
    // ---- region 1: ih gates (r/z accumulate into Chh) + GRU (reg state) ----
    if (task){
      f32x4 Ci2a=(f32x4)0.0f, Ci2b=(f32x4)0.0f;
#pragma unroll
      for (int ks=0;ks<4;++ks){
        bf16x8 m0 = *(const bf16x8*)&XmH[n0*XMS + ks*32 + boff];
        bf16x8 m1 = *(const bf16x8*)&XmH[n1*XMS + ks*32 + boff];
        Chh[0][0] = MFMA(Ai[0][ks], m0, Chh[0][0]);   // gi_r + gh_r fused
        Chh[0][1] = MFMA(Ai[0][ks], m1, Chh[0][1]);
        Chh[1][0] = MFMA(Ai[1][ks], m0, Chh[1][0]);   // gi_z + gh_z fused
        Chh[1][1] = MFMA(Ai[1][ks], m1, Chh[1][1]);
        Ci2a      = MFMA(Ai[2][ks], m0, Ci2a);        // gi_n separate
        Ci2b      = MFMA(Ai[2][ks], m1, Ci2b);
      }
      if (rowbase < 100){
        bool k0 = sh_msk[n0] != 0, k1 = sh_msk[n1] != 0;
        short4 pk0, pk1;
#pragma unroll
        for (int r=0;r<4;++r){
          {
            float ho = hst0[r];
            float rr = sigmoidf_(Chh[0][0][r] + bs0[r]);
            float zz = sigmoidf_(Chh[1][0][r] + bs1[r]);
            float nn = tanhf_(Ci2a[r] + bi2[r] + rr*(Chh[2][0][r] + bh2[r]));
            float hnew = (1.0f-zz)*nn + zz*ho;
            if (!k0) hnew = ho;
            hst0[r] = hnew;
            ((short*)&pk0)[r] = f2bf(hnew);
          }
          {
            float ho = hst1[r];
            float rr = sigmoidf_(Chh[0][1][r] + bs0[r]);
            float zz = sigmoidf_(Chh[1][1][r] + bs1[r]);
            float nn = tanhf_(Ci2b[r] + bi2[r] + rr*(Chh[2][1][r] + bh2[r]));
            float hnew = (1.0f-zz)*nn + zz*ho;
            if (!k1) hnew = ho;
            hst1[r] = hnew;
            ((short*)&pk1)[r] = f2bf(hnew);
          }
        }
        *(short4*)&XcH[n0*XCS + rowbase] = pk0;
        *(short4*)&XcH[n1*XCS + rowbase] = pk1;
      }
    } else if (w == 7){
      // wave 7: stage Wo chunk (interval 2*pass+1)
      int iv = pass*2 + 1;
      for (int i4 = iv*544 + lane; i4 < 3200 && i4 < (iv+1)*544; i4 += 64)
        ((float4*)WoL)[i4] = ((const float4*)Wo)[i4];
    }
    __syncthreads();
  }

  // ---- readout: gate/emb GEMMs (A hi+lo), both halves, masked sum ----------
  if (task){
    const short* pb0 = XcH + n0*XCS + boff;
    const short* pb1 = XcH + n1*XCS + boff;
    bf16x8 rb0[5], rb1[5];
#pragma unroll
    for (int ks=0;ks<5;++ks){
      rb0[ks] = *(const bf16x8*)(pb0 + ks*32);
      rb1[ks] = *(const bf16x8*)(pb1 + ks*32);
    }
    f32x4 Cg0=(f32x4)0.0f, Cg1=(f32x4)0.0f, Ce0=(f32x4)0.0f, Ce1=(f32x4)0.0f;
    {  // Wg: blocks 280+jmt*5 .. +4 (hi) and same-idx lo, K=140
      const short* ph = AFhi + ((size_t)(280 + jmt*5))*512 + lane*8;
      const short* pl = AFlo + ((size_t)(jmt*5))*512 + lane*8;
#pragma unroll
      for (int ks=0;ks<5;++ks){
        bf16x8 ah = *(const bf16x8*)(ph + ks*512);
        bf16x8 al = *(const bf16x8*)(pl + ks*512);
        Cg0 = MFMA(ah, rb0[ks], Cg0); Cg0 = MFMA(al, rb0[ks], Cg0);
        Cg1 = MFMA(ah, rb1[ks], Cg1); Cg1 = MFMA(al, rb1[ks], Cg1);
      }
    }
    {  // We: blocks 315+jmt*4 .. +3 (hi), lo at (blk-280)
      const short* ph = AFhi + ((size_t)(315 + jmt*4))*512 + lane*8;
      const short* pl = AFlo + ((size_t)(35 + jmt*4))*512 + lane*8;
#pragma unroll
      for (int ks=0;ks<4;++ks){
        bf16x8 ah = *(const bf16x8*)(ph + ks*512);
        bf16x8 al = *(const bf16x8*)(pl + ks*512);
        Ce0 = MFMA(ah, rb0[ks], Ce0); Ce0 = MFMA(al, rb0[ks], Ce0);
        Ce1 = MFMA(ah, rb1[ks], Ce1); Ce1 = MFMA(al, rb1[ks], Ce1);
      }
    }
    bool k0 = sh_msk[n0] != 0, k1 = sh_msk[n1] != 0;
#pragma unroll
    for (int r=0;r<4;++r){
      int row = rowbase + r;
      float v0 = 0.0f, v1 = 0.0f;
      if (row<100){
        float g0 = sigmoidf_(Cg0[r] + bg[row]);
        float g1 = sigmoidf_(Cg1[r] + bg[row]);
        float e0 = g0*(Ce0[r] + be[row]);
        float e1 = g1*(Ce1[r] + be[row]);
        v0 = k0 ? e0 : 0.0f;
        v1 = k1 ? e1 : 0.0f;
      }
      float v = v0 + v1;                       // halves sum into same graph-emb
      v += __shfl_xor(v, 1);                   // reduce across 16 cols
      v += __shfl_xor(v, 2);
      v += __shfl_xor(v, 4);
      v += __shfl_xor(v, 8);
      if (row<100 && (lane&15)==0) atomicAdd(&sh_ge[row], v);
    }
  }
  __syncthreads();
  // ---- out = graph_emb @ WoL(LDS) + bo : 512 threads, 4 k-chunks of 25 -----
  {
    int o = tid & 127, qq = tid >> 7;          // lanes consecutive in o
    float s = 0.0f;
    int k0 = 25*qq;
#pragma unroll 5
    for (int k=k0; k<k0+25; ++k) s += sh_ge[k]*WoL[k*OUT_+o];
    sh_part[qq][o] = s;
  }
  __syncthreads();
  if (tid < OUT_){
    out[(size_t)b*OUT_ + tid] = bo[tid] + sh_part[0][tid] + sh_part[1][tid]
                              + sh_part[2][tid] + sh_part[3][tid];
  }
}

extern "C" void kernel_launch(void* const* d_in, const int* in_sizes, int n_in,
                              void* d_out, int out_size, void* d_ws, size_t ws_size,
                              hipStream_t stream){
  const float* nodes = (const float*)d_in[0];
  const float* edges = (const float*)d_in[1];
  const float* W_msg = (const float*)d_in[2];
  const float* W_ih  = (const float*)d_in[3];
  const float* W_hh  = (const float*)d_in[4];
  const float* b_ih  = (const float*)d_in[5];
  const float* b_hh  = (const float*)d_in[6];
  const float* Wg    = (const float*)d_in[7];
  const float* bg    = (const float*)d_in[8];
  const float* We    = (const float*)d_in[9];
  const float* be    = (const float*)d_in[10];
  const float* Wo    = (const float*)d_in[11];
  const float* bo    = (const float*)d_in[12];

  short* AFhi = (short*)d_ws;                        // 343*512 shorts = 343 KB
  short* AFlo = AFhi + (size_t)NBLK*512;             //  63*512 shorts =  63 KB

  prep_frags4<<<(NBLK*512 + 255)/256, 256, 0, stream>>>(W_msg, W_ih, W_hh, Wg, We,
                                                        AFhi, AFlo);
  mpnn_mfma<<<B_, TB, 0, stream>>>(nodes, edges, AFhi, AFlo, b_ih, b_hh, bg, be,
                                   Wo, bo, (float*)d_out);
}